// Round 1
// baseline (189.239 us; speedup 1.0000x reference)
//
#include <hip/hip_runtime.h>
#include <math.h>

// Problem constants (from reference)
#define T_LEN 512
#define DF 64
#define ROW_ELEMS (T_LEN * DF)   // 32768 floats per row
#define NW_ 4
#define STEP_ 16
#define NPAIR 60                 // NW*(NG+NF)
#define NROWS_G 44               // NW*11 rows used by MMD
#define GSTRIDE (NROWS_G * DF)   // 44*64

// pairs = [(i,j) for i in range(4) for j in range(1,4) if i != j]  -> 9 pairs
__constant__ int c_PI[9] = {0, 0, 0, 1, 1, 2, 2, 3, 3};
__constant__ int c_PJ[9] = {1, 2, 3, 2, 3, 1, 3, 1, 2};

// ---------------------------------------------------------------------------
// Kernel 1 (fused):
//   blocks [0,120): sd[p] = sum_t ||X[p,t]-Y[p,t]||^2  (softdtw collapses to
//                   the diagonal because BANDWIDTH=0.1 keeps only i==j)
//   blocks [120,186): 4x4-row tiles of the gram G[a,b,d] = sum_t Za[t,d]*Zb[t,d]
// ---------------------------------------------------------------------------
__global__ __launch_bounds__(256) void k_pair(const float* __restrict__ data,
                                              const float* __restrict__ teacher,
                                              float* __restrict__ sd,   // 120
                                              float* __restrict__ G)    // 44*44*64
{
    const int b = blockIdx.x;
    const int tid = threadIdx.x;

    if (b < 120) {
        const float* src = (b < 60) ? data : teacher;
        const int p = b % 60;
        const int w = p / 15, k = p % 15;
        const float4* A = (const float4*)(src + (size_t)(w * STEP_) * ROW_ELEMS);
        const float4* O = (const float4*)(src + (size_t)(w * STEP_ + 1 + k) * ROW_ELEMS);
        float acc = 0.f;
        #pragma unroll 4
        for (int i = tid; i < ROW_ELEMS / 4; i += 256) {
            float4 a = A[i], o = O[i];
            float dx = a.x - o.x, dy = a.y - o.y, dz = a.z - o.z, dw = a.w - o.w;
            acc += dx * dx + dy * dy + dz * dz + dw * dw;
        }
        __shared__ float red[256];
        red[tid] = acc;
        __syncthreads();
        for (int s = 128; s > 0; s >>= 1) {
            if (tid < s) red[tid] += red[tid + s];
            __syncthreads();
        }
        if (tid == 0) sd[b] = red[0];
    } else {
        // gram tile: map block -> (ta, tb), ta <= tb, 11 tiles of 4 rows
        int q = b - 120;
        int ta = 0;
        while (q >= 11 - ta) { q -= 11 - ta; ta++; }
        const int tb = ta + q;
        const int d = tid & 63, ty = tid >> 6;
        const int ua0 = ta * 4, ub0 = tb * 4;

        const float* rA[4];
        const float* rB[4];
        #pragma unroll
        for (int i = 0; i < 4; ++i) {
            int ua = ua0 + i;
            rA[i] = data + (size_t)((ua / 11) * STEP_ + (ua % 11)) * ROW_ELEMS;
            int ub = ub0 + i;
            rB[i] = data + (size_t)((ub / 11) * STEP_ + (ub % 11)) * ROW_ELEMS;
        }

        float acc[4][4];
        #pragma unroll
        for (int i = 0; i < 4; ++i)
            #pragma unroll
            for (int j = 0; j < 4; ++j) acc[i][j] = 0.f;

        for (int t = ty; t < T_LEN; t += 4) {
            float av[4], bv[4];
            #pragma unroll
            for (int i = 0; i < 4; ++i) av[i] = rA[i][t * DF + d];
            #pragma unroll
            for (int j = 0; j < 4; ++j) bv[j] = rB[j][t * DF + d];
            #pragma unroll
            for (int i = 0; i < 4; ++i)
                #pragma unroll
                for (int j = 0; j < 4; ++j) acc[i][j] += av[i] * bv[j];
        }

        __shared__ float red2[4][16][DF];   // 16 KB
        #pragma unroll
        for (int i = 0; i < 4; ++i)
            #pragma unroll
            for (int j = 0; j < 4; ++j) red2[ty][i * 4 + j][d] = acc[i][j];
        __syncthreads();

        for (int o = tid; o < 16 * DF; o += 256) {
            const int dd = o & 63;
            const int ij = o >> 6;
            const int i = ij >> 2, j = ij & 3;
            float s = red2[0][ij][dd] + red2[1][ij][dd] + red2[2][ij][dd] + red2[3][ij][dd];
            const int ua = ua0 + i, ub = ub0 + j;
            G[(size_t)ua * GSTRIDE + ub * DF + dd] = s;
            G[(size_t)ub * GSTRIDE + ua * DF + dd] = s;
        }
    }
}

// ---------------------------------------------------------------------------
// Kernel 2: per-pair MMD. 9 blocks. Two phases: bandwidth sum, then the
// 5-scale RBF kernel signed sum.
// ---------------------------------------------------------------------------
__global__ __launch_bounds__(256) void k_mmd(const float* __restrict__ G,
                                             float* __restrict__ mmd)  // 9
{
    const int p = blockIdx.x;
    const int tid = threadIdx.x;
    const int gi = c_PI[p], gj = c_PJ[p];
    const int NTOT = 22 * 22 * DF;  // 30976

    __shared__ float red[256];

    // phase 1: sum of L2 over (22,22,64)
    float s1 = 0.f;
    for (int e = tid; e < NTOT; e += 256) {
        const int d = e & 63;
        const int rem = e >> 6;
        const int bb = rem % 22;
        const int aa = rem / 22;
        const int ua = (aa < 11) ? (gi * 11 + aa) : (gj * 11 + aa - 11);
        const int ub = (bb < 11) ? (gi * 11 + bb) : (gj * 11 + bb - 11);
        const float l2 = G[ua * GSTRIDE + ua * DF + d] + G[ub * GSTRIDE + ub * DF + d]
                       - 2.f * G[ua * GSTRIDE + ub * DF + d];
        s1 += l2;
    }
    red[tid] = s1;
    __syncthreads();
    for (int s = 128; s > 0; s >>= 1) {
        if (tid < s) red[tid] += red[tid + s];
        __syncthreads();
    }
    // bw = sum/(ns^2-ns) / K_MUL^(K_NUM//2) = sum/462/4
    const float bw = red[0] / (462.f * 4.f);
    const float inv0 = 1.f / bw;
    __syncthreads();

    // phase 2: signed kernel sum
    float s2 = 0.f;
    for (int e = tid; e < NTOT; e += 256) {
        const int d = e & 63;
        const int rem = e >> 6;
        const int bb = rem % 22;
        const int aa = rem / 22;
        const int ua = (aa < 11) ? (gi * 11 + aa) : (gj * 11 + aa - 11);
        const int ub = (bb < 11) ? (gi * 11 + bb) : (gj * 11 + bb - 11);
        const float l2 = G[ua * GSTRIDE + ua * DF + d] + G[ub * GSTRIDE + ub * DF + d]
                       - 2.f * G[ua * GSTRIDE + ub * DF + d];
        float kv = 0.f;
        float inv = inv0;
        #pragma unroll
        for (int ii = 0; ii < 5; ++ii) {
            kv += __expf(-l2 * inv);
            inv *= 0.5f;
        }
        s2 += (((aa < 11) == (bb < 11)) ? kv : -kv);
    }
    red[tid] = s2;
    __syncthreads();
    for (int s = 128; s > 0; s >>= 1) {
        if (tid < s) red[tid] += red[tid + s];
        __syncthreads();
    }
    if (tid == 0) mmd[p] = red[0] / (11.f * 11.f * 64.f);
}

// ---------------------------------------------------------------------------
// Kernel 3: scalar finisher (triplet math + final combine)
// ---------------------------------------------------------------------------
__global__ void k_final(const float* __restrict__ sd,
                        const int* __restrict__ lens,
                        const float* __restrict__ mmd,
                        float* __restrict__ out)
{
    if (threadIdx.x != 0 || blockIdx.x != 0) return;

    float total = 0.f;
    for (int w = 0; w < 4; ++w) {
        float ds[15], dt[15];
        for (int k = 0; k < 15; ++k) {
            const float denom = (float)lens[w * STEP_] + (float)lens[w * STEP_ + 1 + k];
            ds[k] = sd[w * 15 + k] / denom;
            dt[k] = sd[60 + w * 15 + k] / denom;
        }
        // dists_t[i][j] = relu(dt_n[i] - dt_g[j]); mx = max
        float mx = 0.f;
        for (int i = 0; i < 10; ++i)
            for (int j = 0; j < 5; ++j) {
                float v = dt[5 + i] - dt[j];
                v = v > 0.f ? v : 0.f;
                mx = fmaxf(mx, v);
            }
        const float scale = (1.0f - 0.1f) / mx;
        float sum_lk = 0.f, nz = 0.f;
        for (int i = 0; i < 10; ++i)
            for (int j = 0; j < 5; ++j) {
                float v = dt[5 + i] - dt[j];
                v = v > 0.f ? v : 0.f;
                const float fd = scale * v + 0.1f;
                float lk = ds[j] - ds[5 + i] + fd;
                lk = lk > 0.f ? lk : 0.f;
                sum_lk += lk;
                if (lk != 0.f) nz += 1.f;
            }
        const float lv = sum_lk / (nz + 1.f);
        const float ca = (ds[0] + ds[1] + ds[2] + ds[3] + ds[4]) * 0.2f;
        const float cb = (ds[5] + ds[6] + ds[7] + ds[8] + ds[9]) * 0.2f;
        const float intra = (ds[0] - ca) + (ds[1] - ca) + (ds[2] - ca) + (ds[3] - ca) + (ds[4] - ca);
        float inter = 1.0f - fabsf(ca - cb);
        inter = inter > 0.f ? inter : 0.f;
        total += lv + intra * 0.1f + inter * 0.1f;
    }
    total *= 0.25f;

    float mmax = 0.f;  // mmds has a padded 0 slot, so max starts at 0
    for (int p = 0; p < 9; ++p) mmax = fmaxf(mmax, mmd[p]);
    out[0] = total + 0.5f * mmax;
}

// ---------------------------------------------------------------------------
extern "C" void kernel_launch(void* const* d_in, const int* in_sizes, int n_in,
                              void* d_out, int out_size, void* d_ws, size_t ws_size,
                              hipStream_t stream) {
    const float* data    = (const float*)d_in[0];
    const int*   lens    = (const int*)d_in[1];
    const float* teacher = (const float*)d_in[2];
    float* out = (float*)d_out;

    float* sd  = (float*)d_ws;        // 120 floats (pad to 128)
    float* G   = sd + 128;            // 44*44*64 = 123904 floats
    float* mmd = G + NROWS_G * GSTRIDE; // 9 floats

    k_pair<<<186, 256, 0, stream>>>(data, teacher, sd, G);
    k_mmd<<<9, 256, 0, stream>>>(G, mmd);
    k_final<<<1, 64, 0, stream>>>(sd, lens, mmd, out);
}

// Round 5
// 127.012 us; speedup vs baseline: 1.4899x; 1.4899x over previous
//
#include <hip/hip_runtime.h>
#include <math.h>

// Problem constants
#define T_LEN 512
#define DF 64
#define ROW_ELEMS (T_LEN * DF)   // 32768 floats per row
#define STEP_ 16
#define NROWS_G 44               // 4 groups * 11 rows
#define GSTRIDE (NROWS_G * DF)

// pairs = [(i,j) for i in range(4) for j in range(1,4) if i != j] -> 9 pairs
__constant__ int c_PI[9] = {0, 0, 0, 1, 1, 2, 2, 3, 3};
__constant__ int c_PJ[9] = {1, 2, 3, 2, 3, 1, 3, 1, 2};

// ---------------------------------------------------------------------------
// k_zero: zero the 29 atomic accumulators (Bsum 16 + diagG 4 + mmdRaw 9)
// ---------------------------------------------------------------------------
__global__ void k_zero(float* __restrict__ Z) {
    if (threadIdx.x < 32) Z[threadIdx.x] = 0.f;
}

// ---------------------------------------------------------------------------
// k_pair (1024 threads):
//   blocks [0,66):   4x4-row gram tiles  G[a,b,d] = sum_t Za[t,d]*Zb[t,d]
//                    + wave-reduced tile sums atomically into Bsum/diagG
//                    (bw for each MMD pair is a linear functional of these)
//   blocks [66,186): sd[p] = sum_t ||X[p,t]-Y[p,t]||^2  (softdtw collapses to
//                    the diagonal because BANDWIDTH=0.1 keeps only i==j)
// ---------------------------------------------------------------------------
__global__ __launch_bounds__(1024) void k_pair(const float* __restrict__ data,
                                               const float* __restrict__ teacher,
                                               float* __restrict__ sd,    // 120
                                               float* __restrict__ G,     // 44*44*64
                                               float* __restrict__ Bsum,  // 16
                                               float* __restrict__ diagG) // 4
{
    const int b = blockIdx.x;
    const int tid = threadIdx.x;

    __shared__ float red2[16][16][DF];   // 64 KB (gram branch)
    __shared__ float red[1024];          // 4 KB  (sd branch)

    if (b < 66) {
        // tile index -> (ta, tb), ta <= tb over 11 row-tiles of 4
        int q = b, ta = 0;
        while (q >= 11 - ta) { q -= 11 - ta; ta++; }
        const int tb = ta + q;
        const int d = tid & 63, ty = tid >> 6;      // ty 0..15
        const int ua0 = ta * 4, ub0 = tb * 4;

        const float* rA[4];
        const float* rB[4];
        #pragma unroll
        for (int i = 0; i < 4; ++i) {
            const int ua = ua0 + i, ub = ub0 + i;
            rA[i] = data + (size_t)((ua / 11) * STEP_ + (ua % 11)) * ROW_ELEMS;
            rB[i] = data + (size_t)((ub / 11) * STEP_ + (ub % 11)) * ROW_ELEMS;
        }

        float acc[4][4];
        #pragma unroll
        for (int i = 0; i < 4; ++i)
            #pragma unroll
            for (int j = 0; j < 4; ++j) acc[i][j] = 0.f;

        #pragma unroll 2
        for (int t = ty; t < T_LEN; t += 16) {
            float av[4], bv[4];
            #pragma unroll
            for (int i = 0; i < 4; ++i) av[i] = rA[i][t * DF + d];
            #pragma unroll
            for (int j = 0; j < 4; ++j) bv[j] = rB[j][t * DF + d];
            #pragma unroll
            for (int i = 0; i < 4; ++i)
                #pragma unroll
                for (int j = 0; j < 4; ++j) acc[i][j] += av[i] * bv[j];
        }

        #pragma unroll
        for (int i = 0; i < 4; ++i)
            #pragma unroll
            for (int j = 0; j < 4; ++j) red2[ty][i * 4 + j][d] = acc[i][j];
        __syncthreads();

        // 1024 threads == 16*64 outputs, one each
        const int ij = tid >> 6;                 // same for all lanes of a wave
        const int i = ij >> 2, j = ij & 3;
        float s = 0.f;
        #pragma unroll
        for (int t2 = 0; t2 < 16; ++t2) s += red2[t2][ij][d];

        const int ua = ua0 + i, ub = ub0 + j;
        G[(size_t)ua * GSTRIDE + ub * DF + d] = s;
        G[(size_t)ub * GSTRIDE + ua * DF + d] = s;

        // wave-reduce over d (64 lanes share one ij)
        float wsum = s;
        #pragma unroll
        for (int off = 32; off > 0; off >>= 1) wsum += __shfl_down(wsum, off);
        if (d == 0) {
            const int ga = ua / 11, gb = ub / 11;
            atomicAdd(&Bsum[ga * 4 + gb], wsum);
            if (ta != tb) atomicAdd(&Bsum[gb * 4 + ga], wsum);
            if (ua == ub) atomicAdd(&diagG[ga], wsum);
        }
    } else {
        const int bb = b - 66;                   // 0..119
        const float* src = (bb < 60) ? data : teacher;
        const int p = bb % 60;
        const int w = p / 15, k = p % 15;
        const float4* A = (const float4*)(src + (size_t)(w * STEP_) * ROW_ELEMS);
        const float4* O = (const float4*)(src + (size_t)(w * STEP_ + 1 + k) * ROW_ELEMS);
        float acc = 0.f;
        #pragma unroll 4
        for (int i = tid; i < ROW_ELEMS / 4; i += 1024) {
            float4 a = A[i], o = O[i];
            float dx = a.x - o.x, dy = a.y - o.y, dz = a.z - o.z, dw = a.w - o.w;
            acc += dx * dx + dy * dy + dz * dz + dw * dw;
        }
        red[tid] = acc;
        __syncthreads();
        for (int s = 512; s > 0; s >>= 1) {
            if (tid < s) red[tid] += red[tid + s];
            __syncthreads();
        }
        if (tid == 0) sd[bb] = red[0];
    }
}

// ---------------------------------------------------------------------------
// k_mmd2: single-phase MMD. grid = 9 pairs * 22 rows. bw comes from the
// 20 precomputed scalars; diag terms LDS-cached; cross terms streamed.
// ---------------------------------------------------------------------------
__global__ __launch_bounds__(256) void k_mmd2(const float* __restrict__ G,
                                              const float* __restrict__ Bsum,
                                              const float* __restrict__ diagG,
                                              float* __restrict__ mmdRaw)  // 9
{
    const int blk = blockIdx.x;
    const int p = blk / 22, aa = blk % 22;
    const int tid = threadIdx.x;
    const int gi = c_PI[p], gj = c_PJ[p];

    const float sumL2 = 44.f * (diagG[gi] + diagG[gj])
        - 2.f * (Bsum[gi * 4 + gi] + Bsum[gi * 4 + gj] +
                 Bsum[gj * 4 + gi] + Bsum[gj * 4 + gj]);
    const float bw = sumL2 / (462.f * 4.f);
    const float inv0 = 1.f / bw;

    __shared__ float diagT[22 * DF];
    for (int e = tid; e < 22 * DF; e += 256) {
        const int bb = e >> 6, d2 = e & 63;
        const int ub = (bb < 11) ? gi * 11 + bb : gj * 11 + bb - 11;
        diagT[e] = G[ub * GSTRIDE + ub * DF + d2];
    }
    __syncthreads();

    const int ua = (aa < 11) ? gi * 11 + aa : gj * 11 + aa - 11;
    const bool sa = (aa < 11);
    const float* crossRow = G + (size_t)ua * GSTRIDE;

    float s2 = 0.f;
    for (int e = tid; e < 22 * DF; e += 256) {
        const int bb = e >> 6, d2 = e & 63;
        const int ub = (bb < 11) ? gi * 11 + bb : gj * 11 + bb - 11;
        const float cr = crossRow[ub * DF + d2];
        const float l2 = diagT[aa * DF + d2] + diagT[e] - 2.f * cr;
        float kv = 0.f, inv = inv0;
        #pragma unroll
        for (int ii = 0; ii < 5; ++ii) { kv += __expf(-l2 * inv); inv *= 0.5f; }
        s2 += ((bb < 11) == sa) ? kv : -kv;
    }

    __shared__ float red[256];
    red[tid] = s2;
    __syncthreads();
    for (int s = 128; s > 0; s >>= 1) {
        if (tid < s) red[tid] += red[tid + s];
        __syncthreads();
    }
    if (tid == 0) atomicAdd(&mmdRaw[p], red[0]);
}

// ---------------------------------------------------------------------------
// k_final: scalar finisher
// ---------------------------------------------------------------------------
__global__ void k_final(const float* __restrict__ sd,
                        const int* __restrict__ lens,
                        const float* __restrict__ mmdRaw,
                        float* __restrict__ out)
{
    if (threadIdx.x != 0 || blockIdx.x != 0) return;

    float total = 0.f;
    for (int w = 0; w < 4; ++w) {
        float ds[15], dt[15];
        for (int k = 0; k < 15; ++k) {
            const float denom = (float)lens[w * STEP_] + (float)lens[w * STEP_ + 1 + k];
            ds[k] = sd[w * 15 + k] / denom;
            dt[k] = sd[60 + w * 15 + k] / denom;
        }
        float mx = 0.f;
        for (int i = 0; i < 10; ++i)
            for (int j = 0; j < 5; ++j) {
                float v = dt[5 + i] - dt[j];
                v = v > 0.f ? v : 0.f;
                mx = fmaxf(mx, v);
            }
        const float scale = (1.0f - 0.1f) / mx;
        float sum_lk = 0.f, nz = 0.f;
        for (int i = 0; i < 10; ++i)
            for (int j = 0; j < 5; ++j) {
                float v = dt[5 + i] - dt[j];
                v = v > 0.f ? v : 0.f;
                const float fd = scale * v + 0.1f;
                float lk = ds[j] - ds[5 + i] + fd;
                lk = lk > 0.f ? lk : 0.f;
                sum_lk += lk;
                if (lk != 0.f) nz += 1.f;
            }
        const float lv = sum_lk / (nz + 1.f);
        const float ca = (ds[0] + ds[1] + ds[2] + ds[3] + ds[4]) * 0.2f;
        const float cb = (ds[5] + ds[6] + ds[7] + ds[8] + ds[9]) * 0.2f;
        const float intra = (ds[0] - ca) + (ds[1] - ca) + (ds[2] - ca) + (ds[3] - ca) + (ds[4] - ca);
        float inter = 1.0f - fabsf(ca - cb);
        inter = inter > 0.f ? inter : 0.f;
        total += lv + intra * 0.1f + inter * 0.1f;
    }
    total *= 0.25f;

    float mmax = 0.f;   // padded zero slot in mmds
    for (int p = 0; p < 9; ++p) mmax = fmaxf(mmax, mmdRaw[p] / (121.f * 64.f));
    out[0] = total + 0.5f * mmax;
}

// ---------------------------------------------------------------------------
extern "C" void kernel_launch(void* const* d_in, const int* in_sizes, int n_in,
                              void* d_out, int out_size, void* d_ws, size_t ws_size,
                              hipStream_t stream) {
    const float* data    = (const float*)d_in[0];
    const int*   lens    = (const int*)d_in[1];
    const float* teacher = (const float*)d_in[2];
    float* out = (float*)d_out;

    float* sd   = (float*)d_ws;                 // 120 (pad 128)
    float* G    = sd + 128;                     // 44*44*64 = 123904
    float* Z    = G + (size_t)NROWS_G * GSTRIDE;// accumulators base
    float* Bsum = Z;                            // 16
    float* diagG= Z + 16;                       // 4
    float* mmdR = Z + 20;                       // 9

    k_zero<<<1, 64, 0, stream>>>(Z);
    k_pair<<<186, 1024, 0, stream>>>(data, teacher, sd, G, Bsum, diagG);
    k_mmd2<<<9 * 22, 256, 0, stream>>>(G, Bsum, diagG, mmdR);
    k_final<<<1, 64, 0, stream>>>(sd, lens, mmdR, out);
}

// Round 7
// 107.201 us; speedup vs baseline: 1.7653x; 1.1848x over previous
//
#include <hip/hip_runtime.h>
#include <math.h>

// Problem constants
#define T_LEN 512
#define DF 64
#define ROW_ELEMS (T_LEN * DF)   // 32768 floats per row
#define STEP_ 16
#define NROWS_G 44               // 4 groups * 11 rows
#define GSTRIDE (NROWS_G * DF)   // 2816

// pairs = [(i,j) for i in range(4) for j in range(1,4) if i != j] -> 9 pairs
__constant__ int c_PI[9] = {0, 0, 0, 1, 1, 2, 2, 3, 3};
__constant__ int c_PJ[9] = {1, 2, 3, 2, 3, 1, 3, 1, 2};

// block-wide sum via wave shuffle + 4-slot LDS (two syncthreads)
__device__ inline float blockSum(float v, float* tmp4) {
    #pragma unroll
    for (int off = 32; off > 0; off >>= 1) v += __shfl_down(v, off);
    if ((threadIdx.x & 63) == 0) tmp4[threadIdx.x >> 6] = v;
    __syncthreads();
    const float s = tmp4[0] + tmp4[1] + tmp4[2] + tmp4[3];
    __syncthreads();
    return s;
}

// ---------------------------------------------------------------------------
// k_pair (1024 threads):
//   blocks [0,66):   4x4-row gram tiles  G[a,b,d] = sum_t Za[t,d]*Zb[t,d]
//   blocks [66,186): sd[p] = sum_t ||X[p,t]-Y[p,t]||^2  (softdtw collapses to
//                    the diagonal because BANDWIDTH=0.1 keeps only i==j)
//   block 0 thread 0 also zeroes the completion counter for k_mmd2 (ordered
//   before k_mmd2 by the kernel boundary).
// ---------------------------------------------------------------------------
__global__ __launch_bounds__(1024) void k_pair(const float* __restrict__ data,
                                               const float* __restrict__ teacher,
                                               float* __restrict__ sd,    // 120
                                               float* __restrict__ G,     // 44*44*64
                                               unsigned* __restrict__ counter)
{
    const int b = blockIdx.x;
    const int tid = threadIdx.x;

    __shared__ float red2[16][16][DF];   // 64 KB (gram branch)
    __shared__ float red[1024];          // 4 KB  (sd branch)

    if (b == 0 && tid == 0) *counter = 0u;

    if (b < 66) {
        // tile index -> (ta, tb), ta <= tb over 11 row-tiles of 4
        int q = b, ta = 0;
        while (q >= 11 - ta) { q -= 11 - ta; ta++; }
        const int tb = ta + q;
        const int d = tid & 63, ty = tid >> 6;      // ty 0..15
        const int ua0 = ta * 4, ub0 = tb * 4;

        const float* rA[4];
        const float* rB[4];
        #pragma unroll
        for (int i = 0; i < 4; ++i) {
            const int ua = ua0 + i, ub = ub0 + i;
            rA[i] = data + (size_t)((ua / 11) * STEP_ + (ua % 11)) * ROW_ELEMS;
            rB[i] = data + (size_t)((ub / 11) * STEP_ + (ub % 11)) * ROW_ELEMS;
        }

        float acc[4][4];
        #pragma unroll
        for (int i = 0; i < 4; ++i)
            #pragma unroll
            for (int j = 0; j < 4; ++j) acc[i][j] = 0.f;

        #pragma unroll 2
        for (int t = ty; t < T_LEN; t += 16) {
            float av[4], bv[4];
            #pragma unroll
            for (int i = 0; i < 4; ++i) av[i] = rA[i][t * DF + d];
            #pragma unroll
            for (int j = 0; j < 4; ++j) bv[j] = rB[j][t * DF + d];
            #pragma unroll
            for (int i = 0; i < 4; ++i)
                #pragma unroll
                for (int j = 0; j < 4; ++j) acc[i][j] += av[i] * bv[j];
        }

        #pragma unroll
        for (int i = 0; i < 4; ++i)
            #pragma unroll
            for (int j = 0; j < 4; ++j) red2[ty][i * 4 + j][d] = acc[i][j];
        __syncthreads();

        // 1024 threads == 16*64 outputs, one each
        const int ij = tid >> 6;
        const int i = ij >> 2, j = ij & 3;
        float s = 0.f;
        #pragma unroll
        for (int t2 = 0; t2 < 16; ++t2) s += red2[t2][ij][d];

        const int ua = ua0 + i, ub = ub0 + j;
        G[(size_t)ua * GSTRIDE + ub * DF + d] = s;
        G[(size_t)ub * GSTRIDE + ua * DF + d] = s;
    } else {
        const int bb = b - 66;                   // 0..119
        const float* src = (bb < 60) ? data : teacher;
        const int p = bb % 60;
        const int w = p / 15, k = p % 15;
        const float4* A = (const float4*)(src + (size_t)(w * STEP_) * ROW_ELEMS);
        const float4* O = (const float4*)(src + (size_t)(w * STEP_ + 1 + k) * ROW_ELEMS);
        float acc = 0.f;
        #pragma unroll 4
        for (int i = tid; i < ROW_ELEMS / 4; i += 1024) {
            float4 a = A[i], o = O[i];
            float dx = a.x - o.x, dy = a.y - o.y, dz = a.z - o.z, dw = a.w - o.w;
            acc += dx * dx + dy * dy + dz * dz + dw * dw;
        }
        red[tid] = acc;
        __syncthreads();
        for (int s = 512; s > 0; s >>= 1) {
            if (tid < s) red[tid] += red[tid + s];
            __syncthreads();
        }
        if (tid == 0) sd[bb] = red[0];
    }
}

// ---------------------------------------------------------------------------
// k_mmd2: one block per (pair, row-of-pair): 9*22 = 198 blocks.
//   Phase A: bandwidth (redundant per block, deterministic): sum the pair's
//            22x22x64 gram sub-block from L2-resident G; diag rows to LDS.
//   Phase B: 5-scale RBF signed sum for this block's row -> partial[blk].
//   Last block (completion counter) reduces partials + runs the triplet
//   finisher and writes out[0].
// ---------------------------------------------------------------------------
__global__ __launch_bounds__(256) void k_mmd2(const float* __restrict__ G,
                                              const float* __restrict__ sd,
                                              const int* __restrict__ lens,
                                              float* __restrict__ partial, // 198
                                              unsigned* __restrict__ counter,
                                              float* __restrict__ out)
{
    const int blk = blockIdx.x;
    const int p = blk / 22, aa = blk % 22;
    const int tid = threadIdx.x;
    const int gi = c_PI[p], gj = c_PJ[p];

    __shared__ float diagT[22 * DF];   // 5.5 KB
    __shared__ float tmp4[4];
    __shared__ float fin[256];
    __shared__ float mmd9[9];
    __shared__ float sdl[120];
    __shared__ int lastFlag;

    // ---- Phase A: diag rows into LDS
    for (int e = tid; e < 22 * DF; e += 256) {
        const int bb = e >> 6, d2 = e & 63;
        const int ub = (bb < 11) ? gi * 11 + bb : gj * 11 + bb - 11;
        diagT[e] = G[(size_t)ub * GSTRIDE + ub * DF + d2];
    }

    // full-pair gram sum: 22 rows x 2 contiguous 11*64-float spans, float4
    // 22 * 2 * 176 = 7744 float4
    float gs = 0.f;
    for (int e = tid; e < 7744; e += 256) {
        const int f4 = e % 176;
        const int sp = (e / 176) & 1;
        const int a2 = e / 352;
        const int ua = (a2 < 11) ? gi * 11 + a2 : gj * 11 + a2 - 11;
        const int colbase = (sp ? gj : gi) * 11 * DF;
        const float4 v = *(const float4*)(G + (size_t)ua * GSTRIDE + colbase + f4 * 4);
        gs += v.x + v.y + v.z + v.w;
    }
    __syncthreads();   // diagT ready

    float dsp = 0.f;
    for (int e = tid; e < 22 * DF; e += 256) dsp += diagT[e];

    const float sumG    = blockSum(gs,  tmp4);
    const float diagSum = blockSum(dsp, tmp4);

    // sum L2 over pair = 44*diagSum - 2*sumG ; bw = sumL2/(462*4)
    const float bw = (44.f * diagSum - 2.f * sumG) / (462.f * 4.f);
    const float inv0 = 1.f / bw;

    // ---- Phase B: signed kernel sum for row aa
    const int ua = (aa < 11) ? gi * 11 + aa : gj * 11 + aa - 11;
    const bool sa = (aa < 11);
    const float* crossRow = G + (size_t)ua * GSTRIDE;

    float s2 = 0.f;
    for (int e = tid; e < 22 * DF; e += 256) {
        const int bb = e >> 6, d2 = e & 63;
        const int ub = (bb < 11) ? gi * 11 + bb : gj * 11 + bb - 11;
        const float cr = crossRow[ub * DF + d2];
        const float l2 = diagT[aa * DF + d2] + diagT[e] - 2.f * cr;
        float kv = 0.f, inv = inv0;
        #pragma unroll
        for (int ii = 0; ii < 5; ++ii) { kv += __expf(-l2 * inv); inv *= 0.5f; }
        s2 += ((bb < 11) == sa) ? kv : -kv;
    }
    const float rowSum = blockSum(s2, tmp4);

    // ---- completion protocol
    if (tid == 0) {
        partial[blk] = rowSum;
        __threadfence();                      // device-scope visibility
        const unsigned old = atomicAdd(counter, 1u);
        lastFlag = (old == 197u);
    }
    __syncthreads();
    if (!lastFlag) return;

    // ---- finisher (last block only)
    float pv = 0.f;
    if (tid < 198) pv = atomicAdd(&partial[tid], 0.f);  // coherent read
    fin[tid] = pv;
    __syncthreads();

    if (tid < 9) {
        float s = 0.f;
        #pragma unroll
        for (int k2 = 0; k2 < 22; ++k2) s += fin[tid * 22 + k2];
        mmd9[tid] = s / (121.f * 64.f);
    }
    if (tid < 120) sdl[tid] = sd[tid];
    __syncthreads();

    if (tid == 0) {
        float total = 0.f;
        for (int w = 0; w < 4; ++w) {
            float ds[15], dt[15];
            for (int k = 0; k < 15; ++k) {
                const float denom = (float)lens[w * STEP_] + (float)lens[w * STEP_ + 1 + k];
                ds[k] = sdl[w * 15 + k] / denom;
                dt[k] = sdl[60 + w * 15 + k] / denom;
            }
            float mx = 0.f;
            for (int i = 0; i < 10; ++i)
                for (int j = 0; j < 5; ++j) {
                    float v = dt[5 + i] - dt[j];
                    v = v > 0.f ? v : 0.f;
                    mx = fmaxf(mx, v);
                }
            const float scale = (1.0f - 0.1f) / mx;
            float sum_lk = 0.f, nz = 0.f;
            for (int i = 0; i < 10; ++i)
                for (int j = 0; j < 5; ++j) {
                    float v = dt[5 + i] - dt[j];
                    v = v > 0.f ? v : 0.f;
                    const float fd = scale * v + 0.1f;
                    float lk = ds[j] - ds[5 + i] + fd;
                    lk = lk > 0.f ? lk : 0.f;
                    sum_lk += lk;
                    if (lk != 0.f) nz += 1.f;
                }
            const float lv = sum_lk / (nz + 1.f);
            const float ca = (ds[0] + ds[1] + ds[2] + ds[3] + ds[4]) * 0.2f;
            const float cb = (ds[5] + ds[6] + ds[7] + ds[8] + ds[9]) * 0.2f;
            const float intra = (ds[0] - ca) + (ds[1] - ca) + (ds[2] - ca) + (ds[3] - ca) + (ds[4] - ca);
            float inter = 1.0f - fabsf(ca - cb);
            inter = inter > 0.f ? inter : 0.f;
            total += lv + intra * 0.1f + inter * 0.1f;
        }
        total *= 0.25f;

        float mmax = 0.f;   // padded zero slot in mmds
        for (int q = 0; q < 9; ++q) mmax = fmaxf(mmax, mmd9[q]);
        out[0] = total + 0.5f * mmax;
    }
}

// ---------------------------------------------------------------------------
extern "C" void kernel_launch(void* const* d_in, const int* in_sizes, int n_in,
                              void* d_out, int out_size, void* d_ws, size_t ws_size,
                              hipStream_t stream) {
    const float* data    = (const float*)d_in[0];
    const int*   lens    = (const int*)d_in[1];
    const float* teacher = (const float*)d_in[2];
    float* out = (float*)d_out;

    float*    sd      = (float*)d_ws;                    // 120 (pad 128)
    float*    G       = sd + 128;                        // 44*44*64 = 123904
    float*    partial = G + (size_t)NROWS_G * GSTRIDE;   // 198 (pad 256)
    unsigned* counter = (unsigned*)(partial + 256);      // 1

    k_pair<<<186, 1024, 0, stream>>>(data, teacher, sd, G, counter);
    k_mmd2<<<9 * 22, 256, 0, stream>>>(G, sd, lens, partial, counter, out);
}

// Round 10
// 102.070 us; speedup vs baseline: 1.8540x; 1.0503x over previous
//
#include <hip/hip_runtime.h>
#include <math.h>

// Problem constants
#define T_LEN 512
#define DF 64
#define ROW_ELEMS (T_LEN * DF)   // 32768 floats per row
#define STEP_ 16
#define NROWS_G 44               // 4 groups * 11 rows
#define GSTRIDE (NROWS_G * DF)   // 2816

// pairs = [(i,j) for i in range(4) for j in range(1,4) if i != j] -> 9 pairs
__constant__ int c_PI[9] = {0, 0, 0, 1, 1, 2, 2, 3, 3};
__constant__ int c_PJ[9] = {1, 2, 3, 2, 3, 1, 3, 1, 2};

// block-wide sum via wave shuffle + 4-slot LDS (two syncthreads); 256 threads
__device__ inline float blockSum(float v, float* tmp4) {
    #pragma unroll
    for (int off = 32; off > 0; off >>= 1) v += __shfl_down(v, off);
    if ((threadIdx.x & 63) == 0) tmp4[threadIdx.x >> 6] = v;
    __syncthreads();
    const float s = tmp4[0] + tmp4[1] + tmp4[2] + tmp4[3];
    __syncthreads();
    return s;
}

// ---------------------------------------------------------------------------
// k_pair (256 threads):
//   blocks [0,132):  gram tiles split over t: block = (tile, t-half).
//                    tile = 4x4 rows; float4 loads along d; partial gram
//                    G_half[a,b,d] = sum_{t in half} Za[t,d]*Zb[t,d]
//   blocks [132,252): sd[p] = sum_t ||X[p,t]-Y[p,t]||^2  (softdtw collapses
//                    to the diagonal: BANDWIDTH=0.1 keeps only i==j)
//   block 0 thread 0 zeroes the completion counter for k_mmd2.
// ---------------------------------------------------------------------------
__global__ __launch_bounds__(256) void k_pair(const float* __restrict__ data,
                                              const float* __restrict__ teacher,
                                              float* __restrict__ sd,   // 120
                                              float* __restrict__ G0,   // 44*44*64
                                              float* __restrict__ G1,   // 44*44*64
                                              unsigned* __restrict__ counter)
{
    const int b = blockIdx.x;
    const int tid = threadIdx.x;

    __shared__ float red2[16][16][DF];   // 64 KB (gram branch)
    __shared__ float redS[256];          // 1 KB  (sd branch)

    if (b == 0 && tid == 0) *counter = 0u;

    if (b < 132) {
        const int tile = b >> 1, half = b & 1;
        int q = tile, ta = 0;
        while (q >= 11 - ta) { q -= 11 - ta; ta++; }
        const int tb = ta + q;
        const int ty = tid >> 4, dq = tid & 15;     // 16x16 threads
        const int ua0 = ta * 4, ub0 = tb * 4;

        const float4* rA[4];
        const float4* rB[4];
        #pragma unroll
        for (int i = 0; i < 4; ++i) {
            const int ua = ua0 + i, ub = ub0 + i;
            rA[i] = (const float4*)(data + (size_t)((ua / 11) * STEP_ + (ua % 11)) * ROW_ELEMS);
            rB[i] = (const float4*)(data + (size_t)((ub / 11) * STEP_ + (ub % 11)) * ROW_ELEMS);
        }

        float acc[4][4][4];
        #pragma unroll
        for (int i = 0; i < 4; ++i)
            #pragma unroll
            for (int j = 0; j < 4; ++j)
                #pragma unroll
                for (int c = 0; c < 4; ++c) acc[i][j][c] = 0.f;

        const int tbase = half * 256 + ty;           // t-half, stride 16
        #pragma unroll 2
        for (int it = 0; it < 16; ++it) {
            const int t = tbase + it * 16;
            float4 av[4], bv[4];
            #pragma unroll
            for (int i = 0; i < 4; ++i) av[i] = rA[i][t * 16 + dq];
            #pragma unroll
            for (int j = 0; j < 4; ++j) bv[j] = rB[j][t * 16 + dq];
            #pragma unroll
            for (int i = 0; i < 4; ++i)
                #pragma unroll
                for (int j = 0; j < 4; ++j) {
                    acc[i][j][0] += av[i].x * bv[j].x;
                    acc[i][j][1] += av[i].y * bv[j].y;
                    acc[i][j][2] += av[i].z * bv[j].z;
                    acc[i][j][3] += av[i].w * bv[j].w;
                }
        }

        #pragma unroll
        for (int i = 0; i < 4; ++i)
            #pragma unroll
            for (int j = 0; j < 4; ++j)
                *(float4*)&red2[ty][i * 4 + j][dq * 4] =
                    make_float4(acc[i][j][0], acc[i][j][1], acc[i][j][2], acc[i][j][3]);
        __syncthreads();

        float* __restrict__ Gh = half ? G1 : G0;
        for (int o = tid; o < 1024; o += 256) {
            const int ij = o >> 6, d = o & 63;
            float s = 0.f;
            #pragma unroll
            for (int t2 = 0; t2 < 16; ++t2) s += red2[t2][ij][d];
            const int ua = ua0 + (ij >> 2), ub = ub0 + (ij & 3);
            Gh[(size_t)ua * GSTRIDE + ub * DF + d] = s;
            Gh[(size_t)ub * GSTRIDE + ua * DF + d] = s;   // same value on diag tiles
        }
    } else {
        const int bb = b - 132;                  // 0..119
        const float* src = (bb < 60) ? data : teacher;
        const int p = bb % 60;
        const int w = p / 15, k = p % 15;
        const float4* A = (const float4*)(src + (size_t)(w * STEP_) * ROW_ELEMS);
        const float4* O = (const float4*)(src + (size_t)(w * STEP_ + 1 + k) * ROW_ELEMS);
        float acc = 0.f;
        #pragma unroll 4
        for (int i = tid; i < ROW_ELEMS / 4; i += 256) {
            float4 a = A[i], o = O[i];
            float dx = a.x - o.x, dy = a.y - o.y, dz = a.z - o.z, dw = a.w - o.w;
            acc += dx * dx + dy * dy + dz * dz + dw * dw;
        }
        redS[tid] = acc;
        __syncthreads();
        for (int s = 128; s > 0; s >>= 1) {
            if (tid < s) redS[tid] += redS[tid + s];
            __syncthreads();
        }
        if (tid == 0) sd[bb] = redS[0];
    }
}

// ---------------------------------------------------------------------------
// k_mmd2: one block per (pair, row-of-pair): 9*22 = 198 blocks.
//   Reads G = G0 + G1 (t-halves). Phase A: bandwidth from the pair's full
//   gram sub-block (L2-hot). Phase B: 5-scale RBF signed sum for this row.
//   Last block (completion counter) reduces partials + triplet finisher.
// ---------------------------------------------------------------------------
__global__ __launch_bounds__(256) void k_mmd2(const float* __restrict__ G0,
                                              const float* __restrict__ G1,
                                              const float* __restrict__ sd,
                                              const int* __restrict__ lens,
                                              float* __restrict__ partial, // 198
                                              unsigned* __restrict__ counter,
                                              float* __restrict__ out)
{
    const int blk = blockIdx.x;
    const int p = blk / 22, aa = blk % 22;
    const int tid = threadIdx.x;
    const int gi = c_PI[p], gj = c_PJ[p];

    __shared__ float diagT[22 * DF];   // 5.5 KB
    __shared__ float tmp4[4];
    __shared__ float fin[256];
    __shared__ float mmd9[9];
    __shared__ float sdl[120];
    __shared__ int lastFlag;

    // ---- Phase A: diag rows (summed halves) into LDS
    for (int e = tid; e < 22 * DF; e += 256) {
        const int bb = e >> 6, d2 = e & 63;
        const int ub = (bb < 11) ? gi * 11 + bb : gj * 11 + bb - 11;
        const size_t off = (size_t)ub * GSTRIDE + ub * DF + d2;
        diagT[e] = G0[off] + G1[off];
    }

    // full-pair gram sum: 22 rows x 2 contiguous 11*64-float spans, float4
    const float4* G0q = (const float4*)G0;
    const float4* G1q = (const float4*)G1;
    float gs = 0.f;
    for (int e = tid; e < 7744; e += 256) {
        const int f4 = e % 176;
        const int sp = (e / 176) & 1;
        const int a2 = e / 352;
        const int ua = (a2 < 11) ? gi * 11 + a2 : gj * 11 + a2 - 11;
        const int colbase = (sp ? gj : gi) * 11 * DF;
        const size_t qi = ((size_t)ua * GSTRIDE + colbase) / 4 + f4;
        const float4 v0 = G0q[qi], v1 = G1q[qi];
        gs += (v0.x + v1.x) + (v0.y + v1.y) + (v0.z + v1.z) + (v0.w + v1.w);
    }
    __syncthreads();   // diagT ready

    float dsp = 0.f;
    for (int e = tid; e < 22 * DF; e += 256) dsp += diagT[e];

    const float sumG    = blockSum(gs,  tmp4);
    const float diagSum = blockSum(dsp, tmp4);

    // sum L2 over pair = 44*diagSum - 2*sumG ; bw = sumL2/(462*4)
    const float bw = (44.f * diagSum - 2.f * sumG) / (462.f * 4.f);
    const float inv0 = 1.f / bw;

    // ---- Phase B: signed kernel sum for row aa (float4 over d)
    const int ua = (aa < 11) ? gi * 11 + aa : gj * 11 + aa - 11;
    const bool sa = (aa < 11);
    const float4* cr0 = (const float4*)(G0 + (size_t)ua * GSTRIDE);
    const float4* cr1 = (const float4*)(G1 + (size_t)ua * GSTRIDE);
    const float4* dTq = (const float4*)diagT;

    float s2 = 0.f;
    for (int e = tid; e < 22 * 16; e += 256) {
        const int bb = e >> 4, dq = e & 15;
        const int ub = (bb < 11) ? gi * 11 + bb : gj * 11 + bb - 11;
        const float4 c0 = cr0[ub * 16 + dq], c1 = cr1[ub * 16 + dq];
        const float4 dB = dTq[e];
        const float4 dA = dTq[aa * 16 + dq];
        float l2[4];
        l2[0] = dA.x + dB.x - 2.f * (c0.x + c1.x);
        l2[1] = dA.y + dB.y - 2.f * (c0.y + c1.y);
        l2[2] = dA.z + dB.z - 2.f * (c0.z + c1.z);
        l2[3] = dA.w + dB.w - 2.f * (c0.w + c1.w);
        float kv = 0.f;
        #pragma unroll
        for (int c = 0; c < 4; ++c) {
            float inv = inv0;
            #pragma unroll
            for (int ii = 0; ii < 5; ++ii) { kv += __expf(-l2[c] * inv); inv *= 0.5f; }
        }
        s2 += ((bb < 11) == sa) ? kv : -kv;
    }
    const float rowSum = blockSum(s2, tmp4);

    // ---- completion protocol
    if (tid == 0) {
        partial[blk] = rowSum;
        __threadfence();                      // device-scope visibility
        const unsigned old = atomicAdd(counter, 1u);
        lastFlag = (old == 197u);
    }
    __syncthreads();
    if (!lastFlag) return;

    // ---- finisher (last block only)
    float pv = 0.f;
    if (tid < 198) pv = atomicAdd(&partial[tid], 0.f);  // coherent read
    fin[tid] = pv;
    __syncthreads();

    if (tid < 9) {
        float s = 0.f;
        #pragma unroll
        for (int k2 = 0; k2 < 22; ++k2) s += fin[tid * 22 + k2];
        mmd9[tid] = s / (121.f * 64.f);
    }
    if (tid < 120) sdl[tid] = sd[tid];
    __syncthreads();

    if (tid == 0) {
        float total = 0.f;
        for (int w = 0; w < 4; ++w) {
            float ds[15], dt[15];
            for (int k = 0; k < 15; ++k) {
                const float denom = (float)lens[w * STEP_] + (float)lens[w * STEP_ + 1 + k];
                ds[k] = sdl[w * 15 + k] / denom;
                dt[k] = sdl[60 + w * 15 + k] / denom;
            }
            float mx = 0.f;
            for (int i = 0; i < 10; ++i)
                for (int j = 0; j < 5; ++j) {
                    float v = dt[5 + i] - dt[j];
                    v = v > 0.f ? v : 0.f;
                    mx = fmaxf(mx, v);
                }
            const float scale = (1.0f - 0.1f) / mx;
            float sum_lk = 0.f, nz = 0.f;
            for (int i = 0; i < 10; ++i)
                for (int j = 0; j < 5; ++j) {
                    float v = dt[5 + i] - dt[j];
                    v = v > 0.f ? v : 0.f;
                    const float fd = scale * v + 0.1f;
                    float lk = ds[j] - ds[5 + i] + fd;
                    lk = lk > 0.f ? lk : 0.f;
                    sum_lk += lk;
                    if (lk != 0.f) nz += 1.f;
                }
            const float lv = sum_lk / (nz + 1.f);
            const float ca = (ds[0] + ds[1] + ds[2] + ds[3] + ds[4]) * 0.2f;
            const float cb = (ds[5] + ds[6] + ds[7] + ds[8] + ds[9]) * 0.2f;
            const float intra = (ds[0] - ca) + (ds[1] - ca) + (ds[2] - ca) + (ds[3] - ca) + (ds[4] - ca);
            float inter = 1.0f - fabsf(ca - cb);
            inter = inter > 0.f ? inter : 0.f;
            total += lv + intra * 0.1f + inter * 0.1f;
        }
        total *= 0.25f;

        float mmax = 0.f;   // padded zero slot in mmds
        for (int q2 = 0; q2 < 9; ++q2) mmax = fmaxf(mmax, mmd9[q2]);
        out[0] = total + 0.5f * mmax;
    }
}

// ---------------------------------------------------------------------------
extern "C" void kernel_launch(void* const* d_in, const int* in_sizes, int n_in,
                              void* d_out, int out_size, void* d_ws, size_t ws_size,
                              hipStream_t stream) {
    const float* data    = (const float*)d_in[0];
    const int*   lens    = (const int*)d_in[1];
    const float* teacher = (const float*)d_in[2];
    float* out = (float*)d_out;

    float*    sd      = (float*)d_ws;                    // 120 (pad 128)
    float*    G0      = sd + 128;                        // 44*44*64 = 123904
    float*    G1      = G0 + (size_t)NROWS_G * GSTRIDE;  // 123904
    float*    partial = G1 + (size_t)NROWS_G * GSTRIDE;  // 198 (pad 256)
    unsigned* counter = (unsigned*)(partial + 256);      // 1

    k_pair<<<252, 256, 0, stream>>>(data, teacher, sd, G0, G1, counter);
    k_mmd2<<<9 * 22, 256, 0, stream>>>(G0, G1, sd, lens, partial, counter, out);
}